// Round 1
// baseline (74.081 us; speedup 1.0000x reference)
//
#include <hip/hip_runtime.h>

#define EPS 1e-10f

constexpr int B_ = 64, K_ = 4, M_ = 3, P_ = 65536;
constexpr int THREADS = 256;
constexpr int CHUNK = 2048;                    // pixels per block
constexpr int BLOCKS_PER_B = P_ / CHUNK;       // 32  -> grid = 2048 blocks
constexpr int VPT = CHUNK / 4 / THREADS;       // float4 iterations per thread = 2
constexpr int NACC = 29;                       // 4 s + 12 t + 12 u + 1 n

// ---------------- pass 1: per-(b,k) weighted sums -------------------------
__global__ __launch_bounds__(THREADS) void gmm_pass1(
    const float* __restrict__ pred, const float* __restrict__ inp,
    const int* __restrict__ heart, float* __restrict__ sums)
{
    const int blk   = blockIdx.x;
    const int b     = blk / BLOCKS_PER_B;
    const int chunk = blk % BLOCKS_PER_B;
    const int tid   = threadIdx.x;

    const float4* pb = (const float4*)(pred + (size_t)b * K_ * P_);
    const float4* ib = (const float4*)(inp  + (size_t)b * M_ * P_);
    const int4*   hb = (const int4*)(heart + (size_t)b * P_);
    const int vbase = chunk * (CHUNK / 4);

    float acc[NACC];
    #pragma unroll
    for (int i = 0; i < NACC; ++i) acc[i] = 0.f;

    #pragma unroll
    for (int it = 0; it < VPT; ++it) {
        const int v = vbase + it * THREADS + tid;
        int4 h4 = hb[v];
        float4 pk[K_];
        float4 xm[M_];
        #pragma unroll
        for (int k = 0; k < K_; ++k) pk[k] = pb[k * (P_ / 4) + v];
        #pragma unroll
        for (int m = 0; m < M_; ++m) xm[m] = ib[m * (P_ / 4) + v];

        #pragma unroll
        for (int j = 0; j < 4; ++j) {
            const int hv = (&h4.x)[j];
            const float w = (hv == 1) ? 1.f : 0.f;
            acc[28] += w;
            #pragma unroll
            for (int k = 0; k < K_; ++k) {
                const float pw = (&pk[k].x)[j] * w;
                acc[k] += pw;
                #pragma unroll
                for (int m = 0; m < M_; ++m) {
                    const float x = (&xm[m].x)[j];
                    acc[4  + k * M_ + m] = fmaf(pw,     x, acc[4  + k * M_ + m]);
                    acc[16 + k * M_ + m] = fmaf(pw * x, x, acc[16 + k * M_ + m]);
                }
            }
        }
    }

    __shared__ float lds[4][NACC];
    const int lane = tid & 63, wid = tid >> 6;
    #pragma unroll
    for (int i = 0; i < NACC; ++i) {
        float v = acc[i];
        for (int off = 32; off; off >>= 1) v += __shfl_down(v, off);
        if (lane == 0) lds[wid][i] = v;
    }
    __syncthreads();
    if (tid < NACC) {
        const float v = lds[0][tid] + lds[1][tid] + lds[2][tid] + lds[3][tid];
        atomicAdd(&sums[b * NACC + tid], v);
    }
}

// ---------------- pass 2: derive mu, 1/(2var), coef, 1/(n*B) --------------
__global__ void gmm_pass2(const float* __restrict__ sums, float* __restrict__ der)
{
    const int t = blockIdx.x * blockDim.x + threadIdx.x;   // = b*K + k
    if (t >= B_ * K_) return;
    const int b = t / K_, k = t % K_;
    const float* sb = sums + b * NACC;
    float* db = der + b * NACC;   // layout: mu[12], iv[12], c[4], invn[1]

    const float s = sb[k] + EPS;
    const float inv_s = 1.f / s;
    float c = 1.f;
    #pragma unroll
    for (int m = 0; m < M_; ++m) {
        const float tkm = sb[4  + k * M_ + m];
        const float ukm = sb[16 + k * M_ + m];
        const float mu  = tkm * inv_s;
        const float var = fmaf(-mu, mu, ukm * inv_s) + EPS;
        db[k * M_ + m]      = mu;
        db[12 + k * M_ + m] = 0.5f / var;
        c *= rsqrtf(6.283185307179586f * var);
    }
    db[24 + k] = c;
    if (k == 0) db[28] = 1.f / (sb[28] * (float)B_);
}

// ---------------- pass 3: mixture log-likelihood, masked mean -------------
__global__ __launch_bounds__(THREADS) void gmm_pass3(
    const float* __restrict__ pred, const float* __restrict__ inp,
    const int* __restrict__ heart, const float* __restrict__ der,
    float* __restrict__ out)
{
    const int blk   = blockIdx.x;
    const int b     = blk / BLOCKS_PER_B;
    const int chunk = blk % BLOCKS_PER_B;
    const int tid   = threadIdx.x;

    const float* db = der + b * NACC;
    float mu[K_][M_], iv[K_][M_], ck[K_];
    #pragma unroll
    for (int k = 0; k < K_; ++k) {
        #pragma unroll
        for (int m = 0; m < M_; ++m) {
            mu[k][m] = db[k * M_ + m];
            iv[k][m] = db[12 + k * M_ + m];
        }
        ck[k] = db[24 + k];
    }
    const float invn = db[28];

    const float4* pb = (const float4*)(pred + (size_t)b * K_ * P_);
    const float4* ib = (const float4*)(inp  + (size_t)b * M_ * P_);
    const int4*   hb = (const int4*)(heart + (size_t)b * P_);
    const int vbase = chunk * (CHUNK / 4);

    float part = 0.f;
    #pragma unroll
    for (int it = 0; it < VPT; ++it) {
        const int v = vbase + it * THREADS + tid;
        int4 h4 = hb[v];
        float4 pk[K_];
        float4 xm[M_];
        #pragma unroll
        for (int k = 0; k < K_; ++k) pk[k] = pb[k * (P_ / 4) + v];
        #pragma unroll
        for (int m = 0; m < M_; ++m) xm[m] = ib[m * (P_ / 4) + v];

        #pragma unroll
        for (int j = 0; j < 4; ++j) {
            const int hv = (&h4.x)[j];
            const float w = (hv == 1) ? 1.f : 0.f;
            float mix = EPS;
            #pragma unroll
            for (int k = 0; k < K_; ++k) {
                float e = 0.f;
                #pragma unroll
                for (int m = 0; m < M_; ++m) {
                    const float d = (&xm[m].x)[j] - mu[k][m];
                    e = fmaf(-(d * d), iv[k][m], e);
                }
                mix = fmaf((&pk[k].x)[j] * ck[k], __expf(e), mix);
            }
            part = fmaf(w, __logf(mix), part);
        }
    }

    // block reduction of ll-sum, one atomic per block
    __shared__ float lds[4];
    const int lane = tid & 63, wid = tid >> 6;
    float v = part;
    for (int off = 32; off; off >>= 1) v += __shfl_down(v, off);
    if (lane == 0) lds[wid] = v;
    __syncthreads();
    if (tid == 0) {
        const float s = lds[0] + lds[1] + lds[2] + lds[3];
        atomicAdd(out, -s * invn);
    }
}

extern "C" void kernel_launch(void* const* d_in, const int* in_sizes, int n_in,
                              void* d_out, int out_size, void* d_ws, size_t ws_size,
                              hipStream_t stream)
{
    const float* pred  = (const float*)d_in[0];
    const float* inp   = (const float*)d_in[1];
    const int*   heart = (const int*)d_in[2];
    float* out = (float*)d_out;
    float* ws  = (float*)d_ws;

    float* sums = ws;                 // B*29 floats
    float* der  = ws + B_ * NACC;     // B*29 floats

    hipMemsetAsync(sums, 0, B_ * NACC * sizeof(float), stream);
    hipMemsetAsync(out,  0, sizeof(float), stream);

    gmm_pass1<<<B_ * BLOCKS_PER_B, THREADS, 0, stream>>>(pred, inp, heart, sums);
    gmm_pass2<<<1, 256, 0, stream>>>(sums, der);
    gmm_pass3<<<B_ * BLOCKS_PER_B, THREADS, 0, stream>>>(pred, inp, heart, der, out);
}